// Round 4
// baseline (1367.842 us; speedup 1.0000x reference)
//
#include <hip/hip_runtime.h>
#include <hip/hip_bf16.h>

#define BATCH 256
#define TLEN  512
#define HID   256
#define NT    512          // thread (jj, half): jj = tid&255 owns hidden unit jj; half = K-split
#define NPAIR 64           // fp16 pairs per thread per gate (half of K=256)

typedef _Float16 v2h __attribute__((ext_vector_type(2)));

#if defined(__HIP_DEVICE_COMPILE__) && __has_builtin(__builtin_amdgcn_fdot2)
#define FDOT2(a, b, c) __builtin_amdgcn_fdot2((a), (b), (c), false)
#else
static __device__ __host__ __forceinline__ float FDOT2(v2h a, v2h b, float c) {
  return (float)a[0] * (float)b[0] + ((float)a[1] * (float)b[1] + c);
}
#endif

__device__ __forceinline__ v2h pair_from_u32(int u) {
  union { int i; v2h h; } cv; cv.i = u; return cv.h;
}

__device__ __forceinline__ float fast_sigmoid(float x) {
  float e = __expf(-x);
  return __builtin_amdgcn_rcpf(1.0f + e);
}
__device__ __forceinline__ float fast_tanh(float x) {
  float e = __expf(-2.0f * x);
  return (1.0f - e) * __builtin_amdgcn_rcpf(1.0f + e);
}

__global__ void
__attribute__((amdgpu_flat_work_group_size(NT, NT), amdgpu_waves_per_eu(2, 2)))
gru_ae_kernel(
    const float* __restrict__ x,
    const float* __restrict__ w_ih_enc, const float* __restrict__ w_hh_enc,
    const float* __restrict__ b_ih_enc, const float* __restrict__ b_hh_enc,
    const float* __restrict__ w_ih_dec, const float* __restrict__ w_hh_dec,
    const float* __restrict__ b_ih_dec, const float* __restrict__ b_hh_dec,
    const float* __restrict__ w_dense, const float* __restrict__ b_dense,
    float* __restrict__ out)
{
  const int b    = blockIdx.x;
  const int tid  = threadIdx.x;
  const int jj   = tid & (HID - 1);   // hidden unit owned (for weights/gate math)
  const int half = tid >> 8;          // 0 or 1: which K-half (wave-uniform)
  const int lane = tid & 63;

  __shared__ __align__(4) _Float16 h16[HID];    // fp16 h, read as 128 u32 pairs
  __shared__ float pr[NT], pz[NT], pn[NT];      // partial dots
  __shared__ float red[HID];                    // dense reduction scratch
  __shared__ float xbuf[TLEN];
  __shared__ float obuf[TLEN];
  __shared__ float xcur_s;

  for (int t = tid; t < TLEN; t += NT) xbuf[t] = x[(size_t)b * TLEN + t];
  if (tid < HID) h16[tid] = (_Float16)0.0f;
  float hreg   = 0.0f;                               // fp32 master h[jj] (tid<HID)
  float wd_reg = (tid < HID) ? w_dense[jj] : 0.0f;
  const float bd = b_dense[0];

  // per-thread weights: rows {jj, H+jj, 2H+jj} of w_hh, cols [half*128, half*128+128)
  v2h wr[NPAIR], wz[NPAIR], wn[NPAIR];
  float wih_r, wih_z, wih_n, br, bz, bin, bhn;

#define LOAD_WEIGHTS(WHH, WIH, BIH, BHH)                                        \
  {                                                                             \
    const float2* r0 = (const float2*)((WHH) + (size_t)(0 * HID + jj) * HID) + half * NPAIR; \
    const float2* z0 = (const float2*)((WHH) + (size_t)(1 * HID + jj) * HID) + half * NPAIR; \
    const float2* n0 = (const float2*)((WHH) + (size_t)(2 * HID + jj) * HID) + half * NPAIR; \
    _Pragma("unroll")                                                           \
    for (int k = 0; k < NPAIR; ++k) {                                           \
      float2 tr = r0[k]; v2h a; a[0] = (_Float16)tr.x; a[1] = (_Float16)tr.y; wr[k] = a; \
      float2 tz = z0[k]; v2h c; c[0] = (_Float16)tz.x; c[1] = (_Float16)tz.y; wz[k] = c; \
      float2 tn = n0[k]; v2h d; d[0] = (_Float16)tn.x; d[1] = (_Float16)tn.y; wn[k] = d; \
    }                                                                           \
    wih_r = (WIH)[jj]; wih_z = (WIH)[HID + jj]; wih_n = (WIH)[2 * HID + jj];    \
    br  = (BIH)[jj] + (BHH)[jj];                                                \
    bz  = (BIH)[HID + jj] + (BHH)[HID + jj];                                    \
    bin = (BIH)[2 * HID + jj];                                                  \
    bhn = (BHH)[2 * HID + jj];                                                  \
  }

  LOAD_WEIGHTS(w_hh_enc, w_ih_enc, b_ih_enc, b_hh_enc);
  __syncthreads();

  // 3 dots over this thread's K-half. h via 1 ds_read_b32 + readlane->SGPR
  // broadcast (v_dot2 takes one SGPR operand) -- no bulk LDS traffic.
  auto dots = [&](float& Dr, float& Dz, float& Dn) {
    const int* hws = (const int*)h16;
    int hword = hws[half * NPAIR + lane];   // lane L holds pair (half*64 + L)
    float ar0 = 0.f, ar1 = 0.f, az0 = 0.f, az1 = 0.f, an0 = 0.f, an1 = 0.f;
#pragma unroll
    for (int k = 0; k < NPAIR; k += 2) {
      v2h h0 = pair_from_u32(__builtin_amdgcn_readlane(hword, k));
      v2h h1 = pair_from_u32(__builtin_amdgcn_readlane(hword, k + 1));
      ar0 = FDOT2(h0, wr[k], ar0); ar1 = FDOT2(h1, wr[k + 1], ar1);
      az0 = FDOT2(h0, wz[k], az0); az1 = FDOT2(h1, wz[k + 1], az1);
      an0 = FDOT2(h0, wn[k], an0); an1 = FDOT2(h1, wn[k + 1], an1);
    }
    Dr = ar0 + ar1; Dz = az0 + az1; Dn = an0 + an1;
  };

  // ---- encoder: 512 steps, 2 barriers each ----
  for (int t = 0; t < TLEN; ++t) {
    float Dr, Dz, Dn;
    dots(Dr, Dz, Dn);
    pr[tid] = Dr; pz[tid] = Dz; pn[tid] = Dn;
    __syncthreads();                                  // (a) partials visible
    if (tid < HID) {
      float dr = pr[tid] + pr[tid + HID];
      float dz = pz[tid] + pz[tid + HID];
      float dn = pn[tid] + pn[tid + HID];
      float xt = xbuf[t];
      float r  = fast_sigmoid(fmaf(xt, wih_r, br) + dr);
      float z  = fast_sigmoid(fmaf(xt, wih_z, bz) + dz);
      float n  = fast_tanh(fmaf(r, dn + bhn, fmaf(xt, wih_n, bin)));
      float hn = n + z * (hreg - n);
      hreg = hn;
      h16[tid] = (_Float16)hn;
    }
    __syncthreads();                                  // (b) h16 visible
  }

  // ---- switch to decoder weights ----
  LOAD_WEIGHTS(w_hh_dec, w_ih_dec, b_ih_dec, b_hh_dec);

  // seed dense reduction with encoder final h
  if (tid < HID) red[tid] = hreg * wd_reg;
  __syncthreads();

  // ---- decoder: 512 autoregressive steps ----
  for (int t = 0; t < TLEN; ++t) {
    // wave 0: reduce red -> x for THIS step (x0 at t=0; output xs[t-1] for t>0)
    if (tid < 64) {
      float s = (red[tid] + red[tid + 64]) + (red[tid + 128] + red[tid + 192]);
      s += __shfl_down(s, 32);
      s += __shfl_down(s, 16);
      s += __shfl_down(s, 8);
      s += __shfl_down(s, 4);
      s += __shfl_down(s, 2);
      s += __shfl_down(s, 1);
      if (tid == 0) {
        float xn = s + bd;
        xcur_s = xn;
        if (t > 0) obuf[t - 1] = xn;
      }
    }
    float Dr, Dz, Dn;
    dots(Dr, Dz, Dn);
    pr[tid] = Dr; pz[tid] = Dz; pn[tid] = Dn;
    __syncthreads();                                  // (a)
    if (tid < HID) {
      float dr = pr[tid] + pr[tid + HID];
      float dz = pz[tid] + pz[tid + HID];
      float dn = pn[tid] + pn[tid + HID];
      float xt = xcur_s;
      float r  = fast_sigmoid(fmaf(xt, wih_r, br) + dr);
      float z  = fast_sigmoid(fmaf(xt, wih_z, bz) + dz);
      float n  = fast_tanh(fmaf(r, dn + bhn, fmaf(xt, wih_n, bin)));
      float hn = n + z * (hreg - n);
      hreg = hn;
      h16[tid] = (_Float16)hn;
      red[tid] = hn * wd_reg;
    }
    __syncthreads();                                  // (b)
  }

  // final output xs[T-1]
  if (tid < 64) {
    float s = (red[tid] + red[tid + 64]) + (red[tid + 128] + red[tid + 192]);
    s += __shfl_down(s, 32);
    s += __shfl_down(s, 16);
    s += __shfl_down(s, 8);
    s += __shfl_down(s, 4);
    s += __shfl_down(s, 2);
    s += __shfl_down(s, 1);
    if (tid == 0) obuf[TLEN - 1] = s + bd;
  }
  __syncthreads();

  // out[b, t] = xs[T-1-t]  (flip)
  for (int t = tid; t < TLEN; t += NT)
    out[(size_t)b * TLEN + t] = obuf[TLEN - 1 - t];
}

extern "C" void kernel_launch(void* const* d_in, const int* in_sizes, int n_in,
                              void* d_out, int out_size, void* d_ws, size_t ws_size,
                              hipStream_t stream) {
  const float* x        = (const float*)d_in[0];
  const float* w_ih_enc = (const float*)d_in[1];
  const float* w_hh_enc = (const float*)d_in[2];
  const float* b_ih_enc = (const float*)d_in[3];
  const float* b_hh_enc = (const float*)d_in[4];
  const float* w_ih_dec = (const float*)d_in[5];
  const float* w_hh_dec = (const float*)d_in[6];
  const float* b_ih_dec = (const float*)d_in[7];
  const float* b_hh_dec = (const float*)d_in[8];
  const float* w_dense  = (const float*)d_in[9];
  const float* b_dense  = (const float*)d_in[10];
  float* out = (float*)d_out;

  hipLaunchKernelGGL(gru_ae_kernel, dim3(BATCH), dim3(NT), 0, stream,
                     x, w_ih_enc, w_hh_enc, b_ih_enc, b_hh_enc,
                     w_ih_dec, w_hh_dec, b_ih_dec, b_hh_dec,
                     w_dense, b_dense, out);
}

// Round 5
// 1361.108 us; speedup vs baseline: 1.0049x; 1.0049x over previous
//
#include <hip/hip_runtime.h>
#include <hip/hip_bf16.h>

#define BATCH 256
#define TLEN  512
#define HID   256
#define NT    512          // thread (jj, half): jj = tid&255 owns hidden unit jj; half = K-split
#define NPAIR 64           // fp16 pairs per thread per gate (half of K=256)

typedef _Float16 v2h __attribute__((ext_vector_type(2)));
typedef int v64i __attribute__((ext_vector_type(64)));   // 64 packed fp16-pairs, pure SSA value

#if defined(__HIP_DEVICE_COMPILE__) && __has_builtin(__builtin_amdgcn_fdot2)
#define FDOT2(a, b, c) __builtin_amdgcn_fdot2((a), (b), (c), false)
#else
static __device__ __host__ __forceinline__ float FDOT2(v2h a, v2h b, float c) {
  return (float)a[0] * (float)b[0] + ((float)a[1] * (float)b[1] + c);
}
#endif

__device__ __forceinline__ v2h pair_from_u32(int u) {
  union { int i; v2h h; } cv; cv.i = u; return cv.h;
}
__device__ __forceinline__ int pack_pair(float x, float y) {
  union { int i; v2h h; } cv; cv.h[0] = (_Float16)x; cv.h[1] = (_Float16)y; return cv.i;
}

__device__ __forceinline__ float fast_sigmoid(float x) {
  float e = __expf(-x);
  return __builtin_amdgcn_rcpf(1.0f + e);
}
__device__ __forceinline__ float fast_tanh(float x) {
  float e = __expf(-2.0f * x);
  return (1.0f - e) * __builtin_amdgcn_rcpf(1.0f + e);
}

__global__ void
__attribute__((amdgpu_flat_work_group_size(NT, NT), amdgpu_waves_per_eu(2, 2)))
gru_ae_kernel(
    const float* __restrict__ x,
    const float* __restrict__ w_ih_enc, const float* __restrict__ w_hh_enc,
    const float* __restrict__ b_ih_enc, const float* __restrict__ b_hh_enc,
    const float* __restrict__ w_ih_dec, const float* __restrict__ w_hh_dec,
    const float* __restrict__ b_ih_dec, const float* __restrict__ b_hh_dec,
    const float* __restrict__ w_dense, const float* __restrict__ b_dense,
    float* __restrict__ out)
{
  const int b    = blockIdx.x;
  const int tid  = threadIdx.x;
  const int jj   = tid & (HID - 1);   // hidden unit owned (for weights/gate math)
  const int half = tid >> 8;          // 0 or 1: which K-half (wave-uniform)
  const int lane = tid & 63;

  __shared__ __align__(4) _Float16 h16[HID];    // fp16 h, read as 128 u32 pairs
  __shared__ float pr[NT], pz[NT], pn[NT];      // partial dots
  __shared__ float red[HID];                    // dense reduction scratch
  __shared__ float xbuf[TLEN];
  __shared__ float obuf[TLEN];
  __shared__ float xcur_s;

  for (int t = tid; t < TLEN; t += NT) xbuf[t] = x[(size_t)b * TLEN + t];
  if (tid < HID) h16[tid] = (_Float16)0.0f;
  float hreg   = 0.0f;                               // fp32 master h[jj] (tid<HID)
  float wd_reg = (tid < HID) ? w_dense[jj] : 0.0f;
  const float bd = b_dense[0];

  // per-thread weights: rows {jj, H+jj, 2H+jj} of w_hh, cols [half*128, half*128+128)
  // held as three 64-word ext-vector SSA values (192 VGPRs) -- NOT allocas.
  v64i wrv, wzv, wnv;
  float wih_r, wih_z, wih_n, br, bz, bin, bhn;

#define LOAD_WEIGHTS(WHH, WIH, BIH, BHH)                                        \
  {                                                                             \
    const float2* r0 = (const float2*)((WHH) + (size_t)(0 * HID + jj) * HID) + half * NPAIR; \
    const float2* z0 = (const float2*)((WHH) + (size_t)(1 * HID + jj) * HID) + half * NPAIR; \
    const float2* n0 = (const float2*)((WHH) + (size_t)(2 * HID + jj) * HID) + half * NPAIR; \
    _Pragma("unroll")                                                           \
    for (int k = 0; k < NPAIR; ++k) {                                           \
      float2 tr = r0[k]; wrv[k] = pack_pair(tr.x, tr.y);                        \
      float2 tz = z0[k]; wzv[k] = pack_pair(tz.x, tz.y);                        \
      float2 tn = n0[k]; wnv[k] = pack_pair(tn.x, tn.y);                        \
    }                                                                           \
    wih_r = (WIH)[jj]; wih_z = (WIH)[HID + jj]; wih_n = (WIH)[2 * HID + jj];    \
    br  = (BIH)[jj] + (BHH)[jj];                                                \
    bz  = (BIH)[HID + jj] + (BHH)[HID + jj];                                    \
    bin = (BIH)[2 * HID + jj];                                                  \
    bhn = (BHH)[2 * HID + jj];                                                  \
  }

  LOAD_WEIGHTS(w_hh_enc, w_ih_enc, b_ih_enc, b_hh_enc);
  __syncthreads();

  // 3 dots over this thread's K-half. h via 1 ds_read_b32 + readlane->SGPR
  // broadcast (v_dot2 takes one SGPR operand) -- no bulk LDS traffic.
  auto dots = [&](float& Dr, float& Dz, float& Dn) {
    const int* hws = (const int*)h16;
    int hword = hws[half * NPAIR + lane];   // lane L holds pair (half*64 + L)
    float ar0 = 0.f, ar1 = 0.f, az0 = 0.f, az1 = 0.f, an0 = 0.f, an1 = 0.f;
#pragma unroll
    for (int k = 0; k < NPAIR; k += 2) {
      v2h h0 = pair_from_u32(__builtin_amdgcn_readlane(hword, k));
      v2h h1 = pair_from_u32(__builtin_amdgcn_readlane(hword, k + 1));
      ar0 = FDOT2(h0, pair_from_u32(wrv[k]), ar0);
      ar1 = FDOT2(h1, pair_from_u32(wrv[k + 1]), ar1);
      az0 = FDOT2(h0, pair_from_u32(wzv[k]), az0);
      az1 = FDOT2(h1, pair_from_u32(wzv[k + 1]), az1);
      an0 = FDOT2(h0, pair_from_u32(wnv[k]), an0);
      an1 = FDOT2(h1, pair_from_u32(wnv[k + 1]), an1);
    }
    Dr = ar0 + ar1; Dz = az0 + az1; Dn = an0 + an1;
  };

  // ---- encoder: 512 steps, 2 barriers each ----
  for (int t = 0; t < TLEN; ++t) {
    float Dr, Dz, Dn;
    dots(Dr, Dz, Dn);
    pr[tid] = Dr; pz[tid] = Dz; pn[tid] = Dn;
    __syncthreads();                                  // (a) partials visible
    if (tid < HID) {
      float dr = pr[tid] + pr[tid + HID];
      float dz = pz[tid] + pz[tid + HID];
      float dn = pn[tid] + pn[tid + HID];
      float xt = xbuf[t];
      float r  = fast_sigmoid(fmaf(xt, wih_r, br) + dr);
      float z  = fast_sigmoid(fmaf(xt, wih_z, bz) + dz);
      float n  = fast_tanh(fmaf(r, dn + bhn, fmaf(xt, wih_n, bin)));
      float hn = n + z * (hreg - n);
      hreg = hn;
      h16[tid] = (_Float16)hn;
    }
    __syncthreads();                                  // (b) h16 visible
  }

  // ---- switch to decoder weights ----
  LOAD_WEIGHTS(w_hh_dec, w_ih_dec, b_ih_dec, b_hh_dec);

  // seed dense reduction with encoder final h
  if (tid < HID) red[tid] = hreg * wd_reg;
  __syncthreads();

  // ---- decoder: 512 autoregressive steps ----
  for (int t = 0; t < TLEN; ++t) {
    // wave 0: reduce red -> x for THIS step (x0 at t=0; output xs[t-1] for t>0)
    if (tid < 64) {
      float s = (red[tid] + red[tid + 64]) + (red[tid + 128] + red[tid + 192]);
      s += __shfl_down(s, 32);
      s += __shfl_down(s, 16);
      s += __shfl_down(s, 8);
      s += __shfl_down(s, 4);
      s += __shfl_down(s, 2);
      s += __shfl_down(s, 1);
      if (tid == 0) {
        float xn = s + bd;
        xcur_s = xn;
        if (t > 0) obuf[t - 1] = xn;
      }
    }
    float Dr, Dz, Dn;
    dots(Dr, Dz, Dn);
    pr[tid] = Dr; pz[tid] = Dz; pn[tid] = Dn;
    __syncthreads();                                  // (a)
    if (tid < HID) {
      float dr = pr[tid] + pr[tid + HID];
      float dz = pz[tid] + pz[tid + HID];
      float dn = pn[tid] + pn[tid + HID];
      float xt = xcur_s;
      float r  = fast_sigmoid(fmaf(xt, wih_r, br) + dr);
      float z  = fast_sigmoid(fmaf(xt, wih_z, bz) + dz);
      float n  = fast_tanh(fmaf(r, dn + bhn, fmaf(xt, wih_n, bin)));
      float hn = n + z * (hreg - n);
      hreg = hn;
      h16[tid] = (_Float16)hn;
      red[tid] = hn * wd_reg;
    }
    __syncthreads();                                  // (b)
  }

  // final output xs[T-1]
  if (tid < 64) {
    float s = (red[tid] + red[tid + 64]) + (red[tid + 128] + red[tid + 192]);
    s += __shfl_down(s, 32);
    s += __shfl_down(s, 16);
    s += __shfl_down(s, 8);
    s += __shfl_down(s, 4);
    s += __shfl_down(s, 2);
    s += __shfl_down(s, 1);
    if (tid == 0) obuf[TLEN - 1] = s + bd;
  }
  __syncthreads();

  // out[b, t] = xs[T-1-t]  (flip)
  for (int t = tid; t < TLEN; t += NT)
    out[(size_t)b * TLEN + t] = obuf[TLEN - 1 - t];
}

extern "C" void kernel_launch(void* const* d_in, const int* in_sizes, int n_in,
                              void* d_out, int out_size, void* d_ws, size_t ws_size,
                              hipStream_t stream) {
  const float* x        = (const float*)d_in[0];
  const float* w_ih_enc = (const float*)d_in[1];
  const float* w_hh_enc = (const float*)d_in[2];
  const float* b_ih_enc = (const float*)d_in[3];
  const float* b_hh_enc = (const float*)d_in[4];
  const float* w_ih_dec = (const float*)d_in[5];
  const float* w_hh_dec = (const float*)d_in[6];
  const float* b_ih_dec = (const float*)d_in[7];
  const float* b_hh_dec = (const float*)d_in[8];
  const float* w_dense  = (const float*)d_in[9];
  const float* b_dense  = (const float*)d_in[10];
  float* out = (float*)d_out;

  hipLaunchKernelGGL(gru_ae_kernel, dim3(BATCH), dim3(NT), 0, stream,
                     x, w_ih_enc, w_hh_enc, b_ih_enc, b_hh_enc,
                     w_ih_dec, w_hh_dec, b_ih_dec, b_hh_dec,
                     w_dense, b_dense, out);
}

// Round 6
// 1308.290 us; speedup vs baseline: 1.0455x; 1.0404x over previous
//
#include <hip/hip_runtime.h>
#include <hip/hip_bf16.h>

#define BATCH 256
#define TLEN  512
#define HID   256
#define NT    512          // thread (jj, half): jj = tid&255 owns hidden unit jj; half = K-split
#define NPAIR 64           // fp16 pairs per thread per gate (half of K=256)

typedef _Float16 v2h __attribute__((ext_vector_type(2)));
typedef int v4i __attribute__((ext_vector_type(4)));   // 4 packed fp16-pairs (legal 128-bit)

#if defined(__HIP_DEVICE_COMPILE__) && __has_builtin(__builtin_amdgcn_fdot2)
#define FDOT2(a, b, c) __builtin_amdgcn_fdot2((a), (b), (c), false)
#else
static __device__ __host__ __forceinline__ float FDOT2(v2h a, v2h b, float c) {
  return (float)a[0] * (float)b[0] + ((float)a[1] * (float)b[1] + c);
}
#endif

__device__ __forceinline__ v2h pair_from_u32(int u) {
  union { int i; v2h h; } cv; cv.i = u; return cv.h;
}
__device__ __forceinline__ int pack_pair(float x, float y) {
  union { int i; v2h h; } cv; cv.h[0] = (_Float16)x; cv.h[1] = (_Float16)y; return cv.i;
}

__device__ __forceinline__ float fast_sigmoid(float x) {
  float e = __expf(-x);
  return __builtin_amdgcn_rcpf(1.0f + e);
}
__device__ __forceinline__ float fast_tanh(float x) {
  float e = __expf(-2.0f * x);
  return (1.0f - e) * __builtin_amdgcn_rcpf(1.0f + e);
}

#define REP16(M) M(0) M(1) M(2) M(3) M(4) M(5) M(6) M(7) \
                 M(8) M(9) M(10) M(11) M(12) M(13) M(14) M(15)

__global__ void
__attribute__((amdgpu_flat_work_group_size(NT, NT), amdgpu_waves_per_eu(2, 2)))
gru_ae_kernel(
    const float* __restrict__ x,
    const float* __restrict__ w_ih_enc, const float* __restrict__ w_hh_enc,
    const float* __restrict__ b_ih_enc, const float* __restrict__ b_hh_enc,
    const float* __restrict__ w_ih_dec, const float* __restrict__ w_hh_dec,
    const float* __restrict__ b_ih_dec, const float* __restrict__ b_hh_dec,
    const float* __restrict__ w_dense, const float* __restrict__ b_dense,
    float* __restrict__ out)
{
  const int b    = blockIdx.x;
  const int tid  = threadIdx.x;
  const int jj   = tid & (HID - 1);   // hidden unit owned (for weights/gate math)
  const int half = tid >> 8;          // 0 or 1: which K-half (wave-uniform)
  const int lane = tid & 63;

  __shared__ __align__(4) _Float16 h16[HID];    // fp16 h, read as 128 u32 pairs
  __shared__ float pr[NT], pz[NT], pn[NT];      // partial dots
  __shared__ float red[HID];                    // dense reduction scratch
  __shared__ float xbuf[TLEN];
  __shared__ float obuf[TLEN];
  __shared__ float xcur_s;

  for (int t = tid; t < TLEN; t += NT) xbuf[t] = x[(size_t)b * TLEN + t];
  if (tid < HID) h16[tid] = (_Float16)0.0f;
  float hreg   = 0.0f;                               // fp32 master h[jj] (tid<HID)
  float wd_reg = (tid < HID) ? w_dense[jj] : 0.0f;
  const float bd = b_dense[0];

  // per-thread weights: rows {jj, H+jj, 2H+jj} of w_hh, cols [half*128, half*128+128)
  // held as 48 NAMED int4 SSA values (192 VGPRs) -- no arrays, no big vectors,
  // nothing for the compiler to demote to scratch.
#define DECLW(c) v4i WR##c, WZ##c, WN##c;
  REP16(DECLW)
#undef DECLW
  float wih_r, wih_z, wih_n, br, bz, bin, bhn;

#define LOADC(c) {                                                              \
    float2 ra0 = r0[4*c+0], ra1 = r0[4*c+1], ra2 = r0[4*c+2], ra3 = r0[4*c+3];  \
    WR##c.x = pack_pair(ra0.x, ra0.y); WR##c.y = pack_pair(ra1.x, ra1.y);       \
    WR##c.z = pack_pair(ra2.x, ra2.y); WR##c.w = pack_pair(ra3.x, ra3.y);       \
    float2 za0 = z0[4*c+0], za1 = z0[4*c+1], za2 = z0[4*c+2], za3 = z0[4*c+3];  \
    WZ##c.x = pack_pair(za0.x, za0.y); WZ##c.y = pack_pair(za1.x, za1.y);       \
    WZ##c.z = pack_pair(za2.x, za2.y); WZ##c.w = pack_pair(za3.x, za3.y);       \
    float2 na0 = n0[4*c+0], na1 = n0[4*c+1], na2 = n0[4*c+2], na3 = n0[4*c+3];  \
    WN##c.x = pack_pair(na0.x, na0.y); WN##c.y = pack_pair(na1.x, na1.y);       \
    WN##c.z = pack_pair(na2.x, na2.y); WN##c.w = pack_pair(na3.x, na3.y);       \
  }

#define LOAD_WEIGHTS(WHH, WIH, BIH, BHH)                                        \
  {                                                                             \
    const float2* r0 = (const float2*)((WHH) + (size_t)(0 * HID + jj) * HID) + half * NPAIR; \
    const float2* z0 = (const float2*)((WHH) + (size_t)(1 * HID + jj) * HID) + half * NPAIR; \
    const float2* n0 = (const float2*)((WHH) + (size_t)(2 * HID + jj) * HID) + half * NPAIR; \
    REP16(LOADC)                                                                \
    wih_r = (WIH)[jj]; wih_z = (WIH)[HID + jj]; wih_n = (WIH)[2 * HID + jj];    \
    br  = (BIH)[jj] + (BHH)[jj];                                                \
    bz  = (BIH)[HID + jj] + (BHH)[HID + jj];                                    \
    bin = (BIH)[2 * HID + jj];                                                  \
    bhn = (BHH)[2 * HID + jj];                                                  \
  }

  // 3 dots over this thread's K-half. h via 1 ds_read_b32 + readlane->SGPR
  // broadcast (v_dot2 takes one SGPR operand) -- no bulk LDS traffic.
#define DOTC(c) {                                                               \
    v2h h0 = pair_from_u32(__builtin_amdgcn_readlane(hword, 4*c+0));            \
    v2h h1 = pair_from_u32(__builtin_amdgcn_readlane(hword, 4*c+1));            \
    v2h h2 = pair_from_u32(__builtin_amdgcn_readlane(hword, 4*c+2));            \
    v2h h3 = pair_from_u32(__builtin_amdgcn_readlane(hword, 4*c+3));            \
    ar0 = FDOT2(h0, pair_from_u32(WR##c.x), ar0);                               \
    ar1 = FDOT2(h1, pair_from_u32(WR##c.y), ar1);                               \
    ar0 = FDOT2(h2, pair_from_u32(WR##c.z), ar0);                               \
    ar1 = FDOT2(h3, pair_from_u32(WR##c.w), ar1);                               \
    az0 = FDOT2(h0, pair_from_u32(WZ##c.x), az0);                               \
    az1 = FDOT2(h1, pair_from_u32(WZ##c.y), az1);                               \
    az0 = FDOT2(h2, pair_from_u32(WZ##c.z), az0);                               \
    az1 = FDOT2(h3, pair_from_u32(WZ##c.w), az1);                               \
    an0 = FDOT2(h0, pair_from_u32(WN##c.x), an0);                               \
    an1 = FDOT2(h1, pair_from_u32(WN##c.y), an1);                               \
    an0 = FDOT2(h2, pair_from_u32(WN##c.z), an0);                               \
    an1 = FDOT2(h3, pair_from_u32(WN##c.w), an1);                               \
  }

#define DOTS(Dr, Dz, Dn) {                                                      \
    int hword = ((const int*)h16)[half * NPAIR + lane];                         \
    float ar0 = 0.f, ar1 = 0.f, az0 = 0.f, az1 = 0.f, an0 = 0.f, an1 = 0.f;     \
    REP16(DOTC)                                                                 \
    Dr = ar0 + ar1; Dz = az0 + az1; Dn = an0 + an1;                             \
  }

  LOAD_WEIGHTS(w_hh_enc, w_ih_enc, b_ih_enc, b_hh_enc);
  __syncthreads();

  // ---- encoder: 512 steps, 2 barriers each ----
  for (int t = 0; t < TLEN; ++t) {
    float Dr, Dz, Dn;
    DOTS(Dr, Dz, Dn);
    pr[tid] = Dr; pz[tid] = Dz; pn[tid] = Dn;
    __syncthreads();                                  // (a) partials visible
    if (tid < HID) {
      float dr = pr[tid] + pr[tid + HID];
      float dz = pz[tid] + pz[tid + HID];
      float dn = pn[tid] + pn[tid + HID];
      float xt = xbuf[t];
      float r  = fast_sigmoid(fmaf(xt, wih_r, br) + dr);
      float z  = fast_sigmoid(fmaf(xt, wih_z, bz) + dz);
      float n  = fast_tanh(fmaf(r, dn + bhn, fmaf(xt, wih_n, bin)));
      float hn = n + z * (hreg - n);
      hreg = hn;
      h16[tid] = (_Float16)hn;
    }
    __syncthreads();                                  // (b) h16 visible
  }

  // ---- switch to decoder weights ----
  LOAD_WEIGHTS(w_hh_dec, w_ih_dec, b_ih_dec, b_hh_dec);

  // seed dense reduction with encoder final h
  if (tid < HID) red[tid] = hreg * wd_reg;
  __syncthreads();

  // ---- decoder: 512 autoregressive steps ----
  for (int t = 0; t < TLEN; ++t) {
    // wave 0: reduce red -> x for THIS step (x0 at t=0; output xs[t-1] for t>0)
    if (tid < 64) {
      float s = (red[tid] + red[tid + 64]) + (red[tid + 128] + red[tid + 192]);
      s += __shfl_down(s, 32);
      s += __shfl_down(s, 16);
      s += __shfl_down(s, 8);
      s += __shfl_down(s, 4);
      s += __shfl_down(s, 2);
      s += __shfl_down(s, 1);
      if (tid == 0) {
        float xn = s + bd;
        xcur_s = xn;
        if (t > 0) obuf[t - 1] = xn;
      }
    }
    float Dr, Dz, Dn;
    DOTS(Dr, Dz, Dn);
    pr[tid] = Dr; pz[tid] = Dz; pn[tid] = Dn;
    __syncthreads();                                  // (a)
    if (tid < HID) {
      float dr = pr[tid] + pr[tid + HID];
      float dz = pz[tid] + pz[tid + HID];
      float dn = pn[tid] + pn[tid + HID];
      float xt = xcur_s;
      float r  = fast_sigmoid(fmaf(xt, wih_r, br) + dr);
      float z  = fast_sigmoid(fmaf(xt, wih_z, bz) + dz);
      float n  = fast_tanh(fmaf(r, dn + bhn, fmaf(xt, wih_n, bin)));
      float hn = n + z * (hreg - n);
      hreg = hn;
      h16[tid] = (_Float16)hn;
      red[tid] = hn * wd_reg;
    }
    __syncthreads();                                  // (b)
  }

  // final output xs[T-1]
  if (tid < 64) {
    float s = (red[tid] + red[tid + 64]) + (red[tid + 128] + red[tid + 192]);
    s += __shfl_down(s, 32);
    s += __shfl_down(s, 16);
    s += __shfl_down(s, 8);
    s += __shfl_down(s, 4);
    s += __shfl_down(s, 2);
    s += __shfl_down(s, 1);
    if (tid == 0) obuf[TLEN - 1] = s + bd;
  }
  __syncthreads();

  // out[b, t] = xs[T-1-t]  (flip)
  for (int t = tid; t < TLEN; t += NT)
    out[(size_t)b * TLEN + t] = obuf[TLEN - 1 - t];
}

extern "C" void kernel_launch(void* const* d_in, const int* in_sizes, int n_in,
                              void* d_out, int out_size, void* d_ws, size_t ws_size,
                              hipStream_t stream) {
  const float* x        = (const float*)d_in[0];
  const float* w_ih_enc = (const float*)d_in[1];
  const float* w_hh_enc = (const float*)d_in[2];
  const float* b_ih_enc = (const float*)d_in[3];
  const float* b_hh_enc = (const float*)d_in[4];
  const float* w_ih_dec = (const float*)d_in[5];
  const float* w_hh_dec = (const float*)d_in[6];
  const float* b_ih_dec = (const float*)d_in[7];
  const float* b_hh_dec = (const float*)d_in[8];
  const float* w_dense  = (const float*)d_in[9];
  const float* b_dense  = (const float*)d_in[10];
  float* out = (float*)d_out;

  hipLaunchKernelGGL(gru_ae_kernel, dim3(BATCH), dim3(NT), 0, stream,
                     x, w_ih_enc, w_hh_enc, b_ih_enc, b_hh_enc,
                     w_ih_dec, w_hh_dec, b_ih_dec, b_hh_dec,
                     w_dense, b_dense, out);
}